// Round 2
// baseline (305.026 us; speedup 1.0000x reference)
//
#include <hip/hip_runtime.h>

typedef unsigned short u16;
typedef __bf16 bf16x8 __attribute__((ext_vector_type(8)));
typedef float f32x4 __attribute__((ext_vector_type(4)));
typedef u16 u16x8 __attribute__((ext_vector_type(8)));

#define S_LEN 2048
#define DMODEL 512
#define NHEAD 8
#define DHEAD 64

static __device__ __forceinline__ u16 f2bf(float f) {
    union { float f; unsigned u; } cv; cv.f = f;
    unsigned u = cv.u;
    return (u16)((u + 0x7fffu + ((u >> 16) & 1u)) >> 16);  // RNE
}
static __device__ __forceinline__ bf16x8 ld8(const u16* p) {
    return *(const bf16x8*)p;
}
static __device__ __forceinline__ float rmax16(float v) {
    v = fmaxf(v, __shfl_xor(v, 1));
    v = fmaxf(v, __shfl_xor(v, 2));
    v = fmaxf(v, __shfl_xor(v, 4));
    v = fmaxf(v, __shfl_xor(v, 8));
    return v;
}
static __device__ __forceinline__ float rsum16(float v) {
    v += __shfl_xor(v, 1);
    v += __shfl_xor(v, 2);
    v += __shfl_xor(v, 4);
    v += __shfl_xor(v, 8);
    return v;
}

// ---------------- fp32 -> bf16 conversion for q/k/v activations ----------------
// grid (1024,1,3), block 256; each thread converts 8 contiguous elements.
__global__ void cvt_qkv_kernel(const float* __restrict__ q, const float* __restrict__ k,
                               const float* __restrict__ v, u16* __restrict__ out) {
    const float* in = (blockIdx.z == 0) ? q : (blockIdx.z == 1) ? k : v;
    u16* o = out + (long)blockIdx.z * 2097152;
    long i = ((long)blockIdx.x * 256 + threadIdx.x) * 8;
    f32x4 a = *(const f32x4*)(in + i);
    f32x4 b = *(const f32x4*)(in + i + 4);
    u16x8 r;
#pragma unroll
    for (int j = 0; j < 4; ++j) { r[j] = f2bf(a[j]); r[4 + j] = f2bf(b[j]); }
    *(u16x8*)(o + i) = r;
}

// ---------------- weights fp32 512x512 -> bf16 W^T (N x K row-major) ----------------
__global__ void transpose_w_kernel(const float* __restrict__ w0, const float* __restrict__ w1,
                                   const float* __restrict__ w2, const float* __restrict__ w3,
                                   u16* __restrict__ out) {
    const float* in;
    switch (blockIdx.z) {
        case 0: in = w0; break;
        case 1: in = w1; break;
        case 2: in = w2; break;
        default: in = w3; break;
    }
    u16* o = out + (long)blockIdx.z * (DMODEL * DMODEL);
    __shared__ float t[32][33];
    int tx = threadIdx.x, ty = threadIdx.y;
    int r = blockIdx.y * 32 + ty, c = blockIdx.x * 32 + tx;
    t[ty][tx] = in[r * DMODEL + c];
    __syncthreads();
    int orow = blockIdx.x * 32 + ty, ocol = blockIdx.y * 32 + tx;
    o[orow * DMODEL + ocol] = f2bf(t[tx][ty]);
}

// V merged bf16 (B,S,512) -> Vt bf16 (B,H,DH,S)
__global__ void transpose_v_kernel(const u16* __restrict__ V, u16* __restrict__ Vt) {
    int z = blockIdx.z;
    int b = z >> 3, h = z & 7;
    const u16* in = V + (long)b * S_LEN * DMODEL + h * DHEAD;
    u16* out = Vt + (long)z * DHEAD * S_LEN;
    __shared__ u16 t[32][33];
    int tx = threadIdx.x, ty = threadIdx.y;
    int r = blockIdx.y * 32 + ty;  // s
    int c = blockIdx.x * 32 + tx;  // d
    t[ty][tx] = in[(long)r * DMODEL + c];
    __syncthreads();
    int orow = blockIdx.x * 32 + ty;  // d
    int ocol = blockIdx.y * 32 + tx;  // s
    out[(long)orow * S_LEN + ocol] = t[tx][ty];
}

// ---------------- GEMM: C(4096x512) = A(4096x512) @ W + bias, W given as Wt (N x K) ----------------
template <bool F32OUT>
static __device__ __forceinline__ void gemm_body(const u16* __restrict__ A,
                                                 const u16* __restrict__ Wt,
                                                 const float* __restrict__ bias,
                                                 void* __restrict__ Cp) {
    const int lane = threadIdx.x & 63;
    const int wave = threadIdx.x >> 6;
    const int wr = wave >> 1, wc = wave & 1;
    const int m0 = blockIdx.y * 128 + wr * 64;
    const int n0 = blockIdx.x * 128 + wc * 64;
    const int cidx = lane & 15;
    const int kg = lane >> 4;

    const u16* aptr[4];
    const u16* bptr[4];
#pragma unroll
    for (int t = 0; t < 4; ++t) {
        aptr[t] = A + (long)(m0 + t * 16 + cidx) * 512 + kg * 8;
        bptr[t] = Wt + (long)(n0 + t * 16 + cidx) * 512 + kg * 8;
    }
    const f32x4 fz = {0.f, 0.f, 0.f, 0.f};
    f32x4 acc[4][4];
#pragma unroll
    for (int i = 0; i < 4; ++i)
#pragma unroll
        for (int j = 0; j < 4; ++j) acc[i][j] = fz;

#pragma unroll 4
    for (int k0 = 0; k0 < 512; k0 += 32) {
        bf16x8 a[4], b[4];
#pragma unroll
        for (int t = 0; t < 4; ++t) a[t] = ld8(aptr[t] + k0);
#pragma unroll
        for (int t = 0; t < 4; ++t) b[t] = ld8(bptr[t] + k0);
#pragma unroll
        for (int i = 0; i < 4; ++i)
#pragma unroll
            for (int j = 0; j < 4; ++j)
                acc[i][j] = __builtin_amdgcn_mfma_f32_16x16x32_bf16(a[i], b[j], acc[i][j], 0, 0, 0);
    }

#pragma unroll
    for (int j = 0; j < 4; ++j) {
        int col = n0 + j * 16 + cidx;
        float bv = bias[col];
#pragma unroll
        for (int i = 0; i < 4; ++i) {
#pragma unroll
            for (int r = 0; r < 4; ++r) {
                int row = m0 + i * 16 + kg * 4 + r;
                if (F32OUT) {
                    ((float*)Cp)[(long)row * 512 + col] = acc[i][j][r] + bv;
                } else {
                    ((u16*)Cp)[(long)row * 512 + col] = f2bf(acc[i][j][r] + bv);
                }
            }
        }
    }
}

__global__ __launch_bounds__(256) void qkv_gemm_kernel(
    const u16* __restrict__ q_in, const u16* __restrict__ k_in, const u16* __restrict__ v_in,
    const u16* __restrict__ wtq, const u16* __restrict__ wtk, const u16* __restrict__ wtv,
    const float* __restrict__ bq, const float* __restrict__ bk, const float* __restrict__ bv,
    u16* __restrict__ Q, u16* __restrict__ K, u16* __restrict__ V) {
    const u16* A;
    const u16* W;
    const float* b;
    u16* C;
    if (blockIdx.z == 0) { A = q_in; W = wtq; b = bq; C = Q; }
    else if (blockIdx.z == 1) { A = k_in; W = wtk; b = bk; C = K; }
    else { A = v_in; W = wtv; b = bv; C = V; }
    gemm_body<false>(A, W, b, C);
}

__global__ __launch_bounds__(256) void out_gemm_kernel(const u16* __restrict__ A,
                                                       const u16* __restrict__ Wt,
                                                       const float* __restrict__ bias,
                                                       float* __restrict__ C) {
    gemm_body<true>(A, Wt, bias, C);
}

// ---------------- flash attention ----------------
// grid: (S/64, B*H), block 256. Wave w owns 16 q-rows.
__global__ __launch_bounds__(256) void attn_kernel(const u16* __restrict__ Q,
                                                   const u16* __restrict__ K,
                                                   const u16* __restrict__ Vt,
                                                   const float* __restrict__ mask,
                                                   u16* __restrict__ Ob) {
    const int lane = threadIdx.x & 63;
    const int wave = threadIdx.x >> 6;
    const int cidx = lane & 15;
    const int kg = lane >> 4;
    const int bh = blockIdx.y;
    const int b = bh >> 3, h = bh & 7;
    const int q0 = blockIdx.x * 64 + wave * 16;

    __shared__ u16 plds[4][16][72];  // per-wave P tile, padded rows (144B, 16B-aligned)
    u16(*pw)[72] = plds[wave];

    // Q fragments (A-layout): row = q0 + cidx, k = kg*8 + j (+32 for 2nd half)
    const long qbase = ((long)(b * S_LEN + q0 + cidx)) * DMODEL + h * DHEAD + kg * 8;
    bf16x8 aq0 = ld8(Q + qbase);
    bf16x8 aq1 = ld8(Q + qbase + 32);

    const f32x4 fz = {0.f, 0.f, 0.f, 0.f};
    f32x4 acc[4];
#pragma unroll
    for (int nt = 0; nt < 4; ++nt) acc[nt] = fz;
    float mrow[4] = {-1e30f, -1e30f, -1e30f, -1e30f};
    float lrow[4] = {0.f, 0.f, 0.f, 0.f};

    const u16* kbase = K + (long)b * S_LEN * DMODEL + h * DHEAD + kg * 8;
    const u16* vtb = Vt + (long)bh * DHEAD * S_LEN;
    const float* mbase = mask + (long)b * S_LEN * S_LEN;

    for (int kt = 0; kt < S_LEN; kt += 64) {
        // S tile = Q K^T : 16 x 64
        f32x4 sacc[4];
#pragma unroll
        for (int ct = 0; ct < 4; ++ct) sacc[ct] = fz;
#pragma unroll
        for (int ct = 0; ct < 4; ++ct) {
            const u16* kp = kbase + (long)(kt + ct * 16 + cidx) * DMODEL;
            bf16x8 bk0 = ld8(kp);
            bf16x8 bk1 = ld8(kp + 32);
            sacc[ct] = __builtin_amdgcn_mfma_f32_16x16x32_bf16(aq0, bk0, sacc[ct], 0, 0, 0);
            sacc[ct] = __builtin_amdgcn_mfma_f32_16x16x32_bf16(aq1, bk1, sacc[ct], 0, 0, 0);
        }
        // scale + additive mask (mask fp32, value 0 or 1; scores += mask * -1e9)
        float sv[4][4];
#pragma unroll
        for (int ct = 0; ct < 4; ++ct) {
#pragma unroll
            for (int r = 0; r < 4; ++r) {
                int mr = q0 + kg * 4 + r;
                int mc = kt + ct * 16 + cidx;
                float mval = mbase[(long)mr * S_LEN + mc];
                sv[ct][r] = sacc[ct][r] * 0.125f - 1e9f * mval;
            }
        }
        // online softmax per owned row
        float pv[4][4];
#pragma unroll
        for (int r = 0; r < 4; ++r) {
            float mx = sv[0][r];
            mx = fmaxf(mx, sv[1][r]);
            mx = fmaxf(mx, sv[2][r]);
            mx = fmaxf(mx, sv[3][r]);
            mx = rmax16(mx);
            float mnew = fmaxf(mrow[r], mx);
            float alpha = __expf(mrow[r] - mnew);
            mrow[r] = mnew;
            float s = 0.f;
#pragma unroll
            for (int ct = 0; ct < 4; ++ct) {
                float p = __expf(sv[ct][r] - mnew);
                pv[ct][r] = p;
                s += p;
            }
            s = rsum16(s);
            lrow[r] = lrow[r] * alpha + s;
#pragma unroll
            for (int nt = 0; nt < 4; ++nt) acc[nt][r] = acc[nt][r] * alpha;
        }
        // P: C-layout -> LDS -> A-layout
#pragma unroll
        for (int ct = 0; ct < 4; ++ct)
#pragma unroll
            for (int r = 0; r < 4; ++r) pw[kg * 4 + r][ct * 16 + cidx] = f2bf(pv[ct][r]);
        __syncthreads();
        bf16x8 pf0 = ld8(&pw[cidx][kg * 8]);
        bf16x8 pf1 = ld8(&pw[cidx][32 + kg * 8]);
        // O += P V
#pragma unroll
        for (int nt = 0; nt < 4; ++nt) {
            const u16* vp = vtb + (long)(nt * 16 + cidx) * S_LEN + kt + kg * 8;
            bf16x8 v0 = ld8(vp);
            bf16x8 v1 = ld8(vp + 32);
            acc[nt] = __builtin_amdgcn_mfma_f32_16x16x32_bf16(pf0, v0, acc[nt], 0, 0, 0);
            acc[nt] = __builtin_amdgcn_mfma_f32_16x16x32_bf16(pf1, v1, acc[nt], 0, 0, 0);
        }
        __syncthreads();
    }
    // epilogue: normalize, write merged (B,S,512) bf16
#pragma unroll
    for (int nt = 0; nt < 4; ++nt) {
#pragma unroll
        for (int r = 0; r < 4; ++r) {
            int row = q0 + kg * 4 + r;
            int col = h * DHEAD + nt * 16 + cidx;
            Ob[((long)(b * S_LEN + row)) * DMODEL + col] = f2bf(acc[nt][r] / lrow[r]);
        }
    }
}

extern "C" void kernel_launch(void* const* d_in, const int* in_sizes, int n_in,
                              void* d_out, int out_size, void* d_ws, size_t ws_size,
                              hipStream_t stream) {
    const float* q_in = (const float*)d_in[0];
    const float* k_in = (const float*)d_in[1];
    const float* v_in = (const float*)d_in[2];
    const float* mask = (const float*)d_in[3];
    const float* wq = (const float*)d_in[4];
    const float* bq = (const float*)d_in[5];
    const float* wk = (const float*)d_in[6];
    const float* bk = (const float*)d_in[7];
    const float* wv = (const float*)d_in[8];
    const float* bv = (const float*)d_in[9];
    const float* wo = (const float*)d_in[10];
    const float* bo = (const float*)d_in[11];

    u16* ws = (u16*)d_ws;
    u16* wt_q = ws;                    // 4 x 512*512 bf16
    u16* wt_k = wt_q + 262144;
    u16* wt_v = wt_k + 262144;
    u16* wt_o = wt_v + 262144;
    u16* Aq = wt_o + 262144;           // converted activations, each 2*2048*512 bf16
    u16* Ak = Aq + 2097152;
    u16* Av = Ak + 2097152;
    u16* Qb = Av + 2097152;            // projected Q/K/V bf16
    u16* Kb = Qb + 2097152;
    u16* Vb = Kb + 2097152;
    u16* Vt = Vb + 2097152;            // V transposed (B,H,DH,S)
    u16* Ab = Vt + 2097152;            // attention output (merged heads) bf16

    dim3 tb(32, 32);
    cvt_qkv_kernel<<<dim3(1024, 1, 3), 256, 0, stream>>>(q_in, k_in, v_in, Aq);
    transpose_w_kernel<<<dim3(16, 16, 4), tb, 0, stream>>>(wq, wk, wv, wo, wt_q);
    qkv_gemm_kernel<<<dim3(4, 32, 3), 256, 0, stream>>>(Aq, Ak, Av, wt_q, wt_k, wt_v,
                                                        bq, bk, bv, Qb, Kb, Vb);
    transpose_v_kernel<<<dim3(2, 64, 16), tb, 0, stream>>>(Vb, Vt);
    attn_kernel<<<dim3(32, 16), 256, 0, stream>>>(Qb, Kb, Vt, mask, Ab);
    out_gemm_kernel<<<dim3(4, 32), 256, 0, stream>>>(Ab, wt_o, bo, (float*)d_out);
}

// Round 3
// 249.015 us; speedup vs baseline: 1.2249x; 1.2249x over previous
//
#include <hip/hip_runtime.h>

typedef unsigned short u16;
typedef __bf16 bf16x8 __attribute__((ext_vector_type(8)));
typedef float f32x4 __attribute__((ext_vector_type(4)));
typedef u16 u16x8 __attribute__((ext_vector_type(8)));

#define S_LEN 2048
#define DMODEL 512
#define NHEAD 8
#define DHEAD 64
#define KSPLIT 2
#define KRANGE (S_LEN / KSPLIT)  // 1024 k-positions per block

static __device__ __forceinline__ float bf2f(u16 v) {
    union { unsigned u; float f; } cv; cv.u = ((unsigned)v) << 16; return cv.f;
}
static __device__ __forceinline__ u16 f2bf(float f) {
    union { float f; unsigned u; } cv; cv.f = f;
    unsigned u = cv.u;
    return (u16)((u + 0x7fffu + ((u >> 16) & 1u)) >> 16);  // RNE
}
static __device__ __forceinline__ bf16x8 ld8(const u16* p) {
    return *(const bf16x8*)p;
}
static __device__ __forceinline__ float rmax16(float v) {
    v = fmaxf(v, __shfl_xor(v, 1));
    v = fmaxf(v, __shfl_xor(v, 2));
    v = fmaxf(v, __shfl_xor(v, 4));
    v = fmaxf(v, __shfl_xor(v, 8));
    return v;
}
static __device__ __forceinline__ float rsum16(float v) {
    v += __shfl_xor(v, 1);
    v += __shfl_xor(v, 2);
    v += __shfl_xor(v, 4);
    v += __shfl_xor(v, 8);
    return v;
}

// ---------------- fp32 -> bf16 conversion for q/k/v activations ----------------
__global__ void cvt_qkv_kernel(const float* __restrict__ q, const float* __restrict__ k,
                               const float* __restrict__ v, u16* __restrict__ out) {
    const float* in = (blockIdx.z == 0) ? q : (blockIdx.z == 1) ? k : v;
    u16* o = out + (long)blockIdx.z * 2097152;
    long i = ((long)blockIdx.x * 256 + threadIdx.x) * 8;
    f32x4 a = *(const f32x4*)(in + i);
    f32x4 b = *(const f32x4*)(in + i + 4);
    u16x8 r;
#pragma unroll
    for (int j = 0; j < 4; ++j) { r[j] = f2bf(a[j]); r[4 + j] = f2bf(b[j]); }
    *(u16x8*)(o + i) = r;
}

// ---------------- weights fp32 512x512 -> bf16 W^T (N x K row-major) ----------------
__global__ void transpose_w_kernel(const float* __restrict__ w0, const float* __restrict__ w1,
                                   const float* __restrict__ w2, const float* __restrict__ w3,
                                   u16* __restrict__ out) {
    const float* in;
    switch (blockIdx.z) {
        case 0: in = w0; break;
        case 1: in = w1; break;
        case 2: in = w2; break;
        default: in = w3; break;
    }
    u16* o = out + (long)blockIdx.z * (DMODEL * DMODEL);
    __shared__ float t[32][33];
    int tx = threadIdx.x, ty = threadIdx.y;
    int r = blockIdx.y * 32 + ty, c = blockIdx.x * 32 + tx;
    t[ty][tx] = in[r * DMODEL + c];
    __syncthreads();
    int orow = blockIdx.x * 32 + ty, ocol = blockIdx.y * 32 + tx;
    o[orow * DMODEL + ocol] = f2bf(t[tx][ty]);
}

// V merged bf16 (B,S,512) -> Vt bf16 (B,H,DH,S)
__global__ void transpose_v_kernel(const u16* __restrict__ V, u16* __restrict__ Vt) {
    int z = blockIdx.z;
    int b = z >> 3, h = z & 7;
    const u16* in = V + (long)b * S_LEN * DMODEL + h * DHEAD;
    u16* out = Vt + (long)z * DHEAD * S_LEN;
    __shared__ u16 t[32][33];
    int tx = threadIdx.x, ty = threadIdx.y;
    int r = blockIdx.y * 32 + ty;  // s
    int c = blockIdx.x * 32 + tx;  // d
    t[ty][tx] = in[(long)r * DMODEL + c];
    __syncthreads();
    int orow = blockIdx.x * 32 + ty;  // d
    int ocol = blockIdx.y * 32 + tx;  // s
    out[(long)orow * S_LEN + ocol] = t[tx][ty];
}

// ---------------- GEMM: C(4096x512) = A(4096x512) @ W + bias, W given as Wt (N x K) ----------------
template <bool F32OUT>
static __device__ __forceinline__ void gemm_body(const u16* __restrict__ A,
                                                 const u16* __restrict__ Wt,
                                                 const float* __restrict__ bias,
                                                 void* __restrict__ Cp) {
    const int lane = threadIdx.x & 63;
    const int wave = threadIdx.x >> 6;
    const int wr = wave >> 1, wc = wave & 1;
    const int m0 = blockIdx.y * 128 + wr * 64;
    const int n0 = blockIdx.x * 128 + wc * 64;
    const int cidx = lane & 15;
    const int kg = lane >> 4;

    const u16* aptr[4];
    const u16* bptr[4];
#pragma unroll
    for (int t = 0; t < 4; ++t) {
        aptr[t] = A + (long)(m0 + t * 16 + cidx) * 512 + kg * 8;
        bptr[t] = Wt + (long)(n0 + t * 16 + cidx) * 512 + kg * 8;
    }
    const f32x4 fz = {0.f, 0.f, 0.f, 0.f};
    f32x4 acc[4][4];
#pragma unroll
    for (int i = 0; i < 4; ++i)
#pragma unroll
        for (int j = 0; j < 4; ++j) acc[i][j] = fz;

#pragma unroll 4
    for (int k0 = 0; k0 < 512; k0 += 32) {
        bf16x8 a[4], b[4];
#pragma unroll
        for (int t = 0; t < 4; ++t) a[t] = ld8(aptr[t] + k0);
#pragma unroll
        for (int t = 0; t < 4; ++t) b[t] = ld8(bptr[t] + k0);
#pragma unroll
        for (int i = 0; i < 4; ++i)
#pragma unroll
            for (int j = 0; j < 4; ++j)
                acc[i][j] = __builtin_amdgcn_mfma_f32_16x16x32_bf16(a[i], b[j], acc[i][j], 0, 0, 0);
    }

#pragma unroll
    for (int j = 0; j < 4; ++j) {
        int col = n0 + j * 16 + cidx;
        float bv = bias[col];
#pragma unroll
        for (int i = 0; i < 4; ++i) {
#pragma unroll
            for (int r = 0; r < 4; ++r) {
                int row = m0 + i * 16 + kg * 4 + r;
                if (F32OUT) {
                    ((float*)Cp)[(long)row * 512 + col] = acc[i][j][r] + bv;
                } else {
                    ((u16*)Cp)[(long)row * 512 + col] = f2bf(acc[i][j][r] + bv);
                }
            }
        }
    }
}

__global__ __launch_bounds__(256) void qkv_gemm_kernel(
    const u16* __restrict__ q_in, const u16* __restrict__ k_in, const u16* __restrict__ v_in,
    const u16* __restrict__ wtq, const u16* __restrict__ wtk, const u16* __restrict__ wtv,
    const float* __restrict__ bq, const float* __restrict__ bk, const float* __restrict__ bv,
    u16* __restrict__ Q, u16* __restrict__ K, u16* __restrict__ V) {
    const u16* A;
    const u16* W;
    const float* b;
    u16* C;
    if (blockIdx.z == 0) { A = q_in; W = wtq; b = bq; C = Q; }
    else if (blockIdx.z == 1) { A = k_in; W = wtk; b = bk; C = K; }
    else { A = v_in; W = wtv; b = bv; C = V; }
    gemm_body<false>(A, W, b, C);
}

__global__ __launch_bounds__(256) void out_gemm_kernel(const u16* __restrict__ A,
                                                       const u16* __restrict__ Wt,
                                                       const float* __restrict__ bias,
                                                       float* __restrict__ C) {
    gemm_body<true>(A, Wt, bias, C);
}

// ---------------- flash attention, K-split with LDS staging ----------------
// grid: (S/64, B*H, KSPLIT), block 256 (4 waves). Wave w owns 16 q-rows.
// Writes unnormalized O partials (bf16) + per-row (m,l) fp32.
__global__ __launch_bounds__(256) void attn_kernel(const u16* __restrict__ Q,
                                                   const u16* __restrict__ K,
                                                   const u16* __restrict__ Vt,
                                                   const float* __restrict__ mask,
                                                   u16* __restrict__ Opart,
                                                   float* __restrict__ ML) {
    const int tid = threadIdx.x;
    const int lane = tid & 63;
    const int wave = tid >> 6;
    const int cidx = lane & 15;
    const int kg = lane >> 4;
    const int bh = blockIdx.y;
    const int b = bh >> 3, h = bh & 7;
    const int q0blk = blockIdx.x * 64;
    const int q0 = q0blk + wave * 16;
    const int z = blockIdx.z;
    const int k0z = z * KRANGE;

    __shared__ u16 kt_lds[64][72];   // [key-local][dh], pitch 72 breaks row-stride conflicts
    __shared__ u16 vt_lds[64][72];   // [dh][key-local]
    __shared__ u16 mk_lds[64][72];   // [q-local][key-local], bf16 mask
    __shared__ u16 p_lds[4][16][72]; // per-wave P tile
    u16(*pw)[72] = p_lds[wave];

    // Q fragments (A-layout): row = q0 + cidx, k = kg*8 + j (+32 for 2nd half)
    const long qbase = ((long)(b * S_LEN + q0 + cidx)) * DMODEL + h * DHEAD + kg * 8;
    bf16x8 aq0 = ld8(Q + qbase);
    bf16x8 aq1 = ld8(Q + qbase + 32);

    const f32x4 fz = {0.f, 0.f, 0.f, 0.f};
    f32x4 acc[4];
#pragma unroll
    for (int nt = 0; nt < 4; ++nt) acc[nt] = fz;
    float mrow[4] = {-1e30f, -1e30f, -1e30f, -1e30f};
    float lrow[4] = {0.f, 0.f, 0.f, 0.f};

    // staging roles
    const int krow0 = tid >> 3, kseg0 = tid & 7;          // pairs 0..255
    const int krow1 = krow0 + 32;                          // pairs 256..511
    const u16* kgbase = K + ((long)(b * S_LEN + k0z)) * DMODEL + h * DHEAD;
    const u16* vgbase = Vt + ((long)bh * DHEAD) * S_LEN + k0z;
    const int mrow_l = tid >> 2, mseg = tid & 3;           // mask: 64 rows x 4 segs of 16
    const float* mgbase = mask + ((long)(b * S_LEN + q0blk + mrow_l)) * S_LEN + k0z + mseg * 16;

    for (int kt = 0; kt < KRANGE; kt += 64) {
        __syncthreads();  // previous iteration's LDS reads complete
        // ---- cooperative staging ----
        *(u16x8*)&kt_lds[krow0][kseg0 * 8] = *(const u16x8*)(kgbase + (long)(kt + krow0) * DMODEL + kseg0 * 8);
        *(u16x8*)&kt_lds[krow1][kseg0 * 8] = *(const u16x8*)(kgbase + (long)(kt + krow1) * DMODEL + kseg0 * 8);
        *(u16x8*)&vt_lds[krow0][kseg0 * 8] = *(const u16x8*)(vgbase + (long)krow0 * S_LEN + kt + kseg0 * 8);
        *(u16x8*)&vt_lds[krow1][kseg0 * 8] = *(const u16x8*)(vgbase + (long)krow1 * S_LEN + kt + kseg0 * 8);
        {
            const float* mp = mgbase + kt;
            f32x4 m0 = *(const f32x4*)(mp);
            f32x4 m1 = *(const f32x4*)(mp + 4);
            f32x4 m2 = *(const f32x4*)(mp + 8);
            f32x4 m3 = *(const f32x4*)(mp + 12);
            u16x8 w0, w1;
#pragma unroll
            for (int j = 0; j < 4; ++j) { w0[j] = f2bf(m0[j]); w0[4 + j] = f2bf(m1[j]); }
#pragma unroll
            for (int j = 0; j < 4; ++j) { w1[j] = f2bf(m2[j]); w1[4 + j] = f2bf(m3[j]); }
            *(u16x8*)&mk_lds[mrow_l][mseg * 16] = w0;
            *(u16x8*)&mk_lds[mrow_l][mseg * 16 + 8] = w1;
        }
        __syncthreads();

        // ---- S tile = Q K^T : 16 x 64 ----
        f32x4 sacc[4];
#pragma unroll
        for (int ct = 0; ct < 4; ++ct) sacc[ct] = fz;
#pragma unroll
        for (int ct = 0; ct < 4; ++ct) {
            bf16x8 bk0 = ld8(&kt_lds[ct * 16 + cidx][kg * 8]);
            bf16x8 bk1 = ld8(&kt_lds[ct * 16 + cidx][32 + kg * 8]);
            sacc[ct] = __builtin_amdgcn_mfma_f32_16x16x32_bf16(aq0, bk0, sacc[ct], 0, 0, 0);
            sacc[ct] = __builtin_amdgcn_mfma_f32_16x16x32_bf16(aq1, bk1, sacc[ct], 0, 0, 0);
        }
        // scale + additive mask
        float sv[4][4];
#pragma unroll
        for (int ct = 0; ct < 4; ++ct) {
#pragma unroll
            for (int r = 0; r < 4; ++r) {
                float mval = bf2f(mk_lds[wave * 16 + kg * 4 + r][ct * 16 + cidx]);
                sv[ct][r] = sacc[ct][r] * 0.125f - 1e9f * mval;
            }
        }
        // online softmax per owned row
        float pvv[4][4];
#pragma unroll
        for (int r = 0; r < 4; ++r) {
            float mx = fmaxf(fmaxf(sv[0][r], sv[1][r]), fmaxf(sv[2][r], sv[3][r]));
            mx = rmax16(mx);
            float mnew = fmaxf(mrow[r], mx);
            float alpha = __expf(mrow[r] - mnew);
            mrow[r] = mnew;
            float s = 0.f;
#pragma unroll
            for (int ct = 0; ct < 4; ++ct) {
                float p = __expf(sv[ct][r] - mnew);
                pvv[ct][r] = p;
                s += p;
            }
            s = rsum16(s);
            lrow[r] = lrow[r] * alpha + s;
#pragma unroll
            for (int nt = 0; nt < 4; ++nt) acc[nt][r] = acc[nt][r] * alpha;
        }
        // P: C-layout -> per-wave LDS -> A-layout (no block barrier needed)
#pragma unroll
        for (int ct = 0; ct < 4; ++ct)
#pragma unroll
            for (int r = 0; r < 4; ++r) pw[kg * 4 + r][ct * 16 + cidx] = f2bf(pvv[ct][r]);
        bf16x8 pf0 = ld8(&pw[cidx][kg * 8]);
        bf16x8 pf1 = ld8(&pw[cidx][32 + kg * 8]);
        // ---- O += P V ----
#pragma unroll
        for (int nt = 0; nt < 4; ++nt) {
            bf16x8 v0 = ld8(&vt_lds[nt * 16 + cidx][kg * 8]);
            bf16x8 v1 = ld8(&vt_lds[nt * 16 + cidx][32 + kg * 8]);
            acc[nt] = __builtin_amdgcn_mfma_f32_16x16x32_bf16(pf0, v0, acc[nt], 0, 0, 0);
            acc[nt] = __builtin_amdgcn_mfma_f32_16x16x32_bf16(pf1, v1, acc[nt], 0, 0, 0);
        }
    }
    // epilogue: write unnormalized partials + (m,l)
#pragma unroll
    for (int nt = 0; nt < 4; ++nt) {
#pragma unroll
        for (int r = 0; r < 4; ++r) {
            int row = q0 + kg * 4 + r;
            Opart[(((long)(z * 16 + bh)) * S_LEN + row) * DHEAD + nt * 16 + cidx] = f2bf(acc[nt][r]);
        }
    }
    if (cidx == 0) {
#pragma unroll
        for (int r = 0; r < 4; ++r) {
            int row = q0 + kg * 4 + r;
            long mi = ((long)(z * 16 + bh)) * S_LEN + row;
            ML[mi * 2] = mrow[r];
            ML[mi * 2 + 1] = lrow[r];
        }
    }
}

// combine KSPLIT partials -> merged bf16 (B,S,512)
__global__ __launch_bounds__(256) void attn_combine_kernel(const u16* __restrict__ Opart,
                                                           const float* __restrict__ ML,
                                                           u16* __restrict__ Ab) {
    const int wave = threadIdx.x >> 6;
    const int col = threadIdx.x & 63;
    const long rr = (long)blockIdx.x * 4 + wave;  // bh*2048 + q
    const int bh = (int)(rr >> 11);
    const int q = (int)(rr & 2047);
    const int b = bh >> 3, h = bh & 7;

    float m0 = ML[(((long)bh) * S_LEN + q) * 2];
    float l0 = ML[(((long)bh) * S_LEN + q) * 2 + 1];
    float m1 = ML[(((long)(16 + bh)) * S_LEN + q) * 2];
    float l1 = ML[(((long)(16 + bh)) * S_LEN + q) * 2 + 1];
    float M = fmaxf(m0, m1);
    float e0 = __expf(m0 - M), e1 = __expf(m1 - M);
    float L = e0 * l0 + e1 * l1;
    float o0 = bf2f(Opart[(((long)bh) * S_LEN + q) * DHEAD + col]);
    float o1 = bf2f(Opart[(((long)(16 + bh)) * S_LEN + q) * DHEAD + col]);
    float o = (e0 * o0 + e1 * o1) / L;
    Ab[((long)(b * S_LEN + q)) * DMODEL + h * DHEAD + col] = f2bf(o);
}

extern "C" void kernel_launch(void* const* d_in, const int* in_sizes, int n_in,
                              void* d_out, int out_size, void* d_ws, size_t ws_size,
                              hipStream_t stream) {
    const float* q_in = (const float*)d_in[0];
    const float* k_in = (const float*)d_in[1];
    const float* v_in = (const float*)d_in[2];
    const float* mask = (const float*)d_in[3];
    const float* wq = (const float*)d_in[4];
    const float* bq = (const float*)d_in[5];
    const float* wk = (const float*)d_in[6];
    const float* bk = (const float*)d_in[7];
    const float* wv = (const float*)d_in[8];
    const float* bv = (const float*)d_in[9];
    const float* wo = (const float*)d_in[10];
    const float* bo = (const float*)d_in[11];

    u16* ws = (u16*)d_ws;
    u16* wt_q = ws;                    // 4 x 512*512 bf16
    u16* wt_k = wt_q + 262144;
    u16* wt_v = wt_k + 262144;
    u16* wt_o = wt_v + 262144;
    u16* Aq = wt_o + 262144;           // converted activations, each 2*2048*512 bf16
    u16* Ak = Aq + 2097152;
    u16* Av = Ak + 2097152;
    u16* Qb = Av + 2097152;            // projected Q/K/V bf16
    u16* Kb = Qb + 2097152;
    u16* Vb = Kb + 2097152;
    u16* Vt = Vb + 2097152;            // V transposed (B,H,DH,S)
    u16* Ab = Vt + 2097152;            // attention output (merged heads) bf16
    // Opart/ML alias the Aq/Ak/Av region (dead after qkv_gemm):
    u16* Opart = Aq;                                   // KSPLIT*16*2048*64 bf16 = 8.4 MB
    float* ML = (float*)(Aq + KSPLIT * 16 * S_LEN * DHEAD);  // KSPLIT*16*2048*2 fp32 = 0.5 MB

    dim3 tb(32, 32);
    cvt_qkv_kernel<<<dim3(1024, 1, 3), 256, 0, stream>>>(q_in, k_in, v_in, Aq);
    transpose_w_kernel<<<dim3(16, 16, 4), tb, 0, stream>>>(wq, wk, wv, wo, wt_q);
    qkv_gemm_kernel<<<dim3(4, 32, 3), 256, 0, stream>>>(Aq, Ak, Av, wt_q, wt_k, wt_v,
                                                        bq, bk, bv, Qb, Kb, Vb);
    transpose_v_kernel<<<dim3(2, 64, 16), tb, 0, stream>>>(Vb, Vt);
    attn_kernel<<<dim3(32, 16, KSPLIT), 256, 0, stream>>>(Qb, Kb, Vt, mask, Opart, ML);
    attn_combine_kernel<<<8192, 256, 0, stream>>>(Opart, ML, Ab);
    out_gemm_kernel<<<dim3(4, 32), 256, 0, stream>>>(Ab, wt_o, bo, (float*)d_out);
}

// Round 4
// 243.457 us; speedup vs baseline: 1.2529x; 1.0228x over previous
//
#include <hip/hip_runtime.h>
#include <hip/hip_bf16.h>

typedef unsigned short u16;
typedef __bf16 bf16x8 __attribute__((ext_vector_type(8)));
typedef float f32x4 __attribute__((ext_vector_type(4)));
typedef u16 u16x8 __attribute__((ext_vector_type(8)));

#define S_LEN 2048
#define DMODEL 512
#define NHEAD 8
#define DHEAD 64
#define KSPLIT 2
#define KRANGE (S_LEN / KSPLIT)  // 1024 k-positions per block

static __device__ __forceinline__ float bf2f(u16 v) {
    union { unsigned u; float f; } cv; cv.u = ((unsigned)v) << 16; return cv.f;
}
static __device__ __forceinline__ u16 f2bf(float f) {
    union { float f; unsigned u; } cv; cv.f = f;
    unsigned u = cv.u;
    return (u16)((u + 0x7fffu + ((u >> 16) & 1u)) >> 16);  // RNE
}
static __device__ __forceinline__ bf16x8 ld8(const u16* p) {
    return *(const bf16x8*)p;
}
static __device__ __forceinline__ float rmax16(float v) {
    v = fmaxf(v, __shfl_xor(v, 1));
    v = fmaxf(v, __shfl_xor(v, 2));
    v = fmaxf(v, __shfl_xor(v, 4));
    v = fmaxf(v, __shfl_xor(v, 8));
    return v;
}
static __device__ __forceinline__ float rsum16(float v) {
    v += __shfl_xor(v, 1);
    v += __shfl_xor(v, 2);
    v += __shfl_xor(v, 4);
    v += __shfl_xor(v, 8);
    return v;
}
// XOR-swizzled LDS index for a [rows][64 u16] tile: 16B blocks permuted by row.
// Row-major 16B staging writes and 16B fragment reads are both <=2-way on banks.
static __device__ __forceinline__ int swz(int row, int col) {
    return row * 64 + ((((col >> 3) ^ (row & 7)) << 3) | (col & 7));
}

// ---------------- fp32 -> bf16 conversion for q/k/v activations ----------------
__global__ void cvt_qkv_kernel(const float* __restrict__ q, const float* __restrict__ k,
                               const float* __restrict__ v, u16* __restrict__ out) {
    const float* in = (blockIdx.z == 0) ? q : (blockIdx.z == 1) ? k : v;
    u16* o = out + (long)blockIdx.z * 2097152;
    long i = ((long)blockIdx.x * 256 + threadIdx.x) * 8;
    f32x4 a = *(const f32x4*)(in + i);
    f32x4 b = *(const f32x4*)(in + i + 4);
    u16x8 r;
#pragma unroll
    for (int j = 0; j < 4; ++j) { r[j] = f2bf(a[j]); r[4 + j] = f2bf(b[j]); }
    *(u16x8*)(o + i) = r;
}

// ---------------- weights fp32 512x512 -> bf16 W^T (N x K row-major) ----------------
__global__ void transpose_w_kernel(const float* __restrict__ w0, const float* __restrict__ w1,
                                   const float* __restrict__ w2, const float* __restrict__ w3,
                                   u16* __restrict__ out) {
    const float* in;
    switch (blockIdx.z) {
        case 0: in = w0; break;
        case 1: in = w1; break;
        case 2: in = w2; break;
        default: in = w3; break;
    }
    u16* o = out + (long)blockIdx.z * (DMODEL * DMODEL);
    __shared__ float t[32][33];
    int tx = threadIdx.x, ty = threadIdx.y;
    int r = blockIdx.y * 32 + ty, c = blockIdx.x * 32 + tx;
    t[ty][tx] = in[r * DMODEL + c];
    __syncthreads();
    int orow = blockIdx.x * 32 + ty, ocol = blockIdx.y * 32 + tx;
    o[orow * DMODEL + ocol] = f2bf(t[tx][ty]);
}

// V merged bf16 (B,S,512) -> Vt bf16 (B,H,DH,S)
__global__ void transpose_v_kernel(const u16* __restrict__ V, u16* __restrict__ Vt) {
    int z = blockIdx.z;
    int b = z >> 3, h = z & 7;
    const u16* in = V + (long)b * S_LEN * DMODEL + h * DHEAD;
    u16* out = Vt + (long)z * DHEAD * S_LEN;
    __shared__ u16 t[32][33];
    int tx = threadIdx.x, ty = threadIdx.y;
    int r = blockIdx.y * 32 + ty;  // s
    int c = blockIdx.x * 32 + tx;  // d
    t[ty][tx] = in[(long)r * DMODEL + c];
    __syncthreads();
    int orow = blockIdx.x * 32 + ty;  // d
    int ocol = blockIdx.y * 32 + tx;  // s
    out[(long)orow * S_LEN + ocol] = t[tx][ty];
}

// ---------------- mask 64x64 block nonzero flags ----------------
// flags[b][qt][kt], qt/kt in 0..31. Memory-bound single pass over the fp32 mask.
__global__ __launch_bounds__(256) void mask_flags_kernel(const float* __restrict__ mask,
                                                         int* __restrict__ flags) {
    const int bid = blockIdx.x;  // 2048 = 2*32*32
    const int b = bid >> 10, qt = (bid >> 5) & 31, kt = bid & 31;
    const int tid = threadIdx.x;
    const int r = tid >> 2, cs = tid & 3;
    const float* p = mask + ((long)(b * S_LEN + qt * 64 + r)) * S_LEN + kt * 64 + cs * 16;
    int nz = 0;
#pragma unroll
    for (int j = 0; j < 4; ++j) {
        f32x4 a = *(const f32x4*)(p + j * 4);
        nz |= (a[0] != 0.f) | (a[1] != 0.f) | (a[2] != 0.f) | (a[3] != 0.f);
    }
    unsigned long long ball = __ballot(nz);
    __shared__ int w[4];
    if ((tid & 63) == 0) w[tid >> 6] = (ball != 0ull) ? 1 : 0;
    __syncthreads();
    if (tid == 0) flags[bid] = w[0] | w[1] | w[2] | w[3];
}

// ---------------- GEMM: C(4096x512) = A(4096x512) @ W + bias, W given as Wt (N x K) ----------------
template <bool F32OUT>
static __device__ __forceinline__ void gemm_body(const u16* __restrict__ A,
                                                 const u16* __restrict__ Wt,
                                                 const float* __restrict__ bias,
                                                 void* __restrict__ Cp, float oscale) {
    const int lane = threadIdx.x & 63;
    const int wave = threadIdx.x >> 6;
    const int wr = wave >> 1, wc = wave & 1;
    const int m0 = blockIdx.y * 128 + wr * 64;
    const int n0 = blockIdx.x * 128 + wc * 64;
    const int cidx = lane & 15;
    const int kg = lane >> 4;

    const u16* aptr[4];
    const u16* bptr[4];
#pragma unroll
    for (int t = 0; t < 4; ++t) {
        aptr[t] = A + (long)(m0 + t * 16 + cidx) * 512 + kg * 8;
        bptr[t] = Wt + (long)(n0 + t * 16 + cidx) * 512 + kg * 8;
    }
    const f32x4 fz = {0.f, 0.f, 0.f, 0.f};
    f32x4 acc[4][4];
#pragma unroll
    for (int i = 0; i < 4; ++i)
#pragma unroll
        for (int j = 0; j < 4; ++j) acc[i][j] = fz;

#pragma unroll 4
    for (int k0 = 0; k0 < 512; k0 += 32) {
        bf16x8 a[4], b[4];
#pragma unroll
        for (int t = 0; t < 4; ++t) a[t] = ld8(aptr[t] + k0);
#pragma unroll
        for (int t = 0; t < 4; ++t) b[t] = ld8(bptr[t] + k0);
#pragma unroll
        for (int i = 0; i < 4; ++i)
#pragma unroll
            for (int j = 0; j < 4; ++j)
                acc[i][j] = __builtin_amdgcn_mfma_f32_16x16x32_bf16(a[i], b[j], acc[i][j], 0, 0, 0);
    }

#pragma unroll
    for (int j = 0; j < 4; ++j) {
        int col = n0 + j * 16 + cidx;
        float bv = bias[col];
#pragma unroll
        for (int i = 0; i < 4; ++i) {
#pragma unroll
            for (int r = 0; r < 4; ++r) {
                int row = m0 + i * 16 + kg * 4 + r;
                float val = (acc[i][j][r] + bv) * oscale;
                if (F32OUT) {
                    ((float*)Cp)[(long)row * 512 + col] = val;
                } else {
                    ((u16*)Cp)[(long)row * 512 + col] = f2bf(val);
                }
            }
        }
    }
}

__global__ __launch_bounds__(256) void qkv_gemm_kernel(
    const u16* __restrict__ q_in, const u16* __restrict__ k_in, const u16* __restrict__ v_in,
    const u16* __restrict__ wtq, const u16* __restrict__ wtk, const u16* __restrict__ wtv,
    const float* __restrict__ bq, const float* __restrict__ bk, const float* __restrict__ bv,
    u16* __restrict__ Q, u16* __restrict__ K, u16* __restrict__ V) {
    const u16* A;
    const u16* W;
    const float* b;
    u16* C;
    float sc = 1.f;
    if (blockIdx.z == 0) { A = q_in; W = wtq; b = bq; C = Q; sc = 0.125f; }  // fold 1/sqrt(DH)
    else if (blockIdx.z == 1) { A = k_in; W = wtk; b = bk; C = K; }
    else { A = v_in; W = wtv; b = bv; C = V; }
    gemm_body<false>(A, W, b, C, sc);
}

__global__ __launch_bounds__(256) void out_gemm_kernel(const u16* __restrict__ A,
                                                       const u16* __restrict__ Wt,
                                                       const float* __restrict__ bias,
                                                       float* __restrict__ C) {
    gemm_body<true>(A, Wt, bias, C, 1.f);
}

// ---------------- flash attention, K-split, swizzled LDS, mask fast-path ----------------
// grid: (S/64, B*H, KSPLIT), block 256 (4 waves). Wave w owns 16 q-rows.
__global__ __launch_bounds__(256) void attn_kernel(const u16* __restrict__ Q,
                                                   const u16* __restrict__ K,
                                                   const u16* __restrict__ Vt,
                                                   const float* __restrict__ mask,
                                                   const int* __restrict__ flags,
                                                   u16* __restrict__ Opart,
                                                   float* __restrict__ ML) {
    const int tid = threadIdx.x;
    const int lane = tid & 63;
    const int wave = tid >> 6;
    const int cidx = lane & 15;
    const int kg = lane >> 4;
    const int bh = blockIdx.y;
    const int b = bh >> 3, h = bh & 7;
    const int q0blk = blockIdx.x * 64;
    const int q0 = q0blk + wave * 16;
    const int z = blockIdx.z;
    const int k0z = z * KRANGE;

    __shared__ u16 kt_lds[64 * 64];   // [key-local][dh], XOR-swizzled
    __shared__ u16 vt_lds[64 * 64];   // [dh][key-local], XOR-swizzled
    __shared__ u16 p_lds[4][16 * 64]; // per-wave P tile, XOR-swizzled
    u16* pw = p_lds[wave];

    // Q fragments (A-layout): row = q0 + cidx, k = kg*8 + j (+32 for 2nd half)
    const long qbase = ((long)(b * S_LEN + q0 + cidx)) * DMODEL + h * DHEAD + kg * 8;
    bf16x8 aq0 = ld8(Q + qbase);
    bf16x8 aq1 = ld8(Q + qbase + 32);

    const f32x4 fz = {0.f, 0.f, 0.f, 0.f};
    f32x4 acc[4];
#pragma unroll
    for (int nt = 0; nt < 4; ++nt) acc[nt] = fz;
    float mrow[4] = {-1e30f, -1e30f, -1e30f, -1e30f};
    float lrow[4] = {0.f, 0.f, 0.f, 0.f};

    // staging roles: 512 16B-pair slots over 256 threads
    const int krow0 = tid >> 3, kseg0 = tid & 7;  // rows 0..31
    const int krow1 = krow0 + 32;                 // rows 32..63
    const u16* kgbase = K + ((long)(b * S_LEN + k0z)) * DMODEL + h * DHEAD;
    const u16* vgbase = Vt + ((long)bh * DHEAD) * S_LEN + k0z;
    const int kd0 = swz(krow0, kseg0 * 8);
    const int kd1 = swz(krow1, kseg0 * 8);
    const int* flagrow = flags + b * 1024 + blockIdx.x * 32 + z * (KRANGE / 64);

    for (int it = 0; it < KRANGE / 64; ++it) {
        const int kt = it * 64;
        const int flg = flagrow[it];
        __syncthreads();  // previous iteration's LDS reads complete
        // ---- cooperative staging (K tile + V tile) ----
        *(u16x8*)&kt_lds[kd0] = *(const u16x8*)(kgbase + (long)(kt + krow0) * DMODEL + kseg0 * 8);
        *(u16x8*)&kt_lds[kd1] = *(const u16x8*)(kgbase + (long)(kt + krow1) * DMODEL + kseg0 * 8);
        *(u16x8*)&vt_lds[kd0] = *(const u16x8*)(vgbase + (long)krow0 * S_LEN + kt + kseg0 * 8);
        *(u16x8*)&vt_lds[kd1] = *(const u16x8*)(vgbase + (long)krow1 * S_LEN + kt + kseg0 * 8);
        __syncthreads();

        // ---- S tile = Q K^T : 16 x 64 (Q pre-scaled by 1/8) ----
        f32x4 sacc[4];
#pragma unroll
        for (int ct = 0; ct < 4; ++ct) sacc[ct] = fz;
#pragma unroll
        for (int ct = 0; ct < 4; ++ct) {
            int r = ct * 16 + cidx;
            bf16x8 bk0 = ld8(&kt_lds[r * 64 + ((kg ^ (r & 7)) << 3)]);
            bf16x8 bk1 = ld8(&kt_lds[r * 64 + (((4 ^ kg) ^ (r & 7)) << 3)]);
            sacc[ct] = __builtin_amdgcn_mfma_f32_16x16x32_bf16(aq0, bk0, sacc[ct], 0, 0, 0);
            sacc[ct] = __builtin_amdgcn_mfma_f32_16x16x32_bf16(aq1, bk1, sacc[ct], 0, 0, 0);
        }
        // mask slow path (rare; fp32 direct from global, exact)
        if (flg) {
            const float* mb = mask + ((long)(b * S_LEN + q0 + kg * 4)) * S_LEN + k0z + kt + cidx;
#pragma unroll
            for (int ct = 0; ct < 4; ++ct)
#pragma unroll
                for (int r = 0; r < 4; ++r)
                    sacc[ct][r] -= 1e9f * mb[(long)r * S_LEN + ct * 16];
        }
        // ---- online softmax per owned row ----
        float pvv[4][4];
#pragma unroll
        for (int r = 0; r < 4; ++r) {
            float mx = fmaxf(fmaxf(sacc[0][r], sacc[1][r]), fmaxf(sacc[2][r], sacc[3][r]));
            mx = rmax16(mx);
            float mnew = fmaxf(mrow[r], mx);
            float alpha = __expf(mrow[r] - mnew);
            mrow[r] = mnew;
            float s = 0.f;
#pragma unroll
            for (int ct = 0; ct < 4; ++ct) {
                float p = __expf(sacc[ct][r] - mnew);
                pvv[ct][r] = p;
                s += p;
            }
            s = rsum16(s);
            lrow[r] = lrow[r] * alpha + s;
#pragma unroll
            for (int nt = 0; nt < 4; ++nt) acc[nt][r] = acc[nt][r] * alpha;
        }
        // ---- P: C-layout -> per-wave LDS (swizzled) -> A-layout ----
#pragma unroll
        for (int ct = 0; ct < 4; ++ct) {
#pragma unroll
            for (int r = 0; r < 4; r += 2) {
                union { __hip_bfloat162 h; unsigned u; } cv;
                float2 f2; f2.x = pvv[ct][r]; f2.y = pvv[ct][r + 1];
                cv.h = __float22bfloat162_rn(f2);
                pw[swz(kg * 4 + r, ct * 16 + cidx)] = (u16)(cv.u & 0xffffu);
                pw[swz(kg * 4 + r + 1, ct * 16 + cidx)] = (u16)(cv.u >> 16);
            }
        }
        bf16x8 pf0 = ld8(&pw[cidx * 64 + ((kg ^ (cidx & 7)) << 3)]);
        bf16x8 pf1 = ld8(&pw[cidx * 64 + (((4 ^ kg) ^ (cidx & 7)) << 3)]);
        // ---- O += P V ----
#pragma unroll
        for (int nt = 0; nt < 4; ++nt) {
            int r = nt * 16 + cidx;
            bf16x8 v0 = ld8(&vt_lds[r * 64 + ((kg ^ (r & 7)) << 3)]);
            bf16x8 v1 = ld8(&vt_lds[r * 64 + (((4 ^ kg) ^ (r & 7)) << 3)]);
            acc[nt] = __builtin_amdgcn_mfma_f32_16x16x32_bf16(pf0, v0, acc[nt], 0, 0, 0);
            acc[nt] = __builtin_amdgcn_mfma_f32_16x16x32_bf16(pf1, v1, acc[nt], 0, 0, 0);
        }
    }
    // epilogue: write unnormalized partials + (m,l)
#pragma unroll
    for (int nt = 0; nt < 4; ++nt) {
#pragma unroll
        for (int r = 0; r < 4; ++r) {
            int row = q0 + kg * 4 + r;
            Opart[(((long)(z * 16 + bh)) * S_LEN + row) * DHEAD + nt * 16 + cidx] = f2bf(acc[nt][r]);
        }
    }
    if (cidx == 0) {
#pragma unroll
        for (int r = 0; r < 4; ++r) {
            int row = q0 + kg * 4 + r;
            long mi = ((long)(z * 16 + bh)) * S_LEN + row;
            ML[mi * 2] = mrow[r];
            ML[mi * 2 + 1] = lrow[r];
        }
    }
}

// combine KSPLIT partials -> merged bf16 (B,S,512)
__global__ __launch_bounds__(256) void attn_combine_kernel(const u16* __restrict__ Opart,
                                                           const float* __restrict__ ML,
                                                           u16* __restrict__ Ab) {
    const int wave = threadIdx.x >> 6;
    const int col = threadIdx.x & 63;
    const long rr = (long)blockIdx.x * 4 + wave;  // bh*2048 + q
    const int bh = (int)(rr >> 11);
    const int q = (int)(rr & 2047);
    const int b = bh >> 3, h = bh & 7;

    float m0 = ML[(((long)bh) * S_LEN + q) * 2];
    float l0 = ML[(((long)bh) * S_LEN + q) * 2 + 1];
    float m1 = ML[(((long)(16 + bh)) * S_LEN + q) * 2];
    float l1 = ML[(((long)(16 + bh)) * S_LEN + q) * 2 + 1];
    float M = fmaxf(m0, m1);
    float e0 = __expf(m0 - M), e1 = __expf(m1 - M);
    float L = e0 * l0 + e1 * l1;
    float o0 = bf2f(Opart[(((long)bh) * S_LEN + q) * DHEAD + col]);
    float o1 = bf2f(Opart[(((long)(16 + bh)) * S_LEN + q) * DHEAD + col]);
    float o = (e0 * o0 + e1 * o1) / L;
    Ab[((long)(b * S_LEN + q)) * DMODEL + h * DHEAD + col] = f2bf(o);
}

extern "C" void kernel_launch(void* const* d_in, const int* in_sizes, int n_in,
                              void* d_out, int out_size, void* d_ws, size_t ws_size,
                              hipStream_t stream) {
    const float* q_in = (const float*)d_in[0];
    const float* k_in = (const float*)d_in[1];
    const float* v_in = (const float*)d_in[2];
    const float* mask = (const float*)d_in[3];
    const float* wq = (const float*)d_in[4];
    const float* bq = (const float*)d_in[5];
    const float* wk = (const float*)d_in[6];
    const float* bk = (const float*)d_in[7];
    const float* wv = (const float*)d_in[8];
    const float* bv = (const float*)d_in[9];
    const float* wo = (const float*)d_in[10];
    const float* bo = (const float*)d_in[11];

    u16* ws = (u16*)d_ws;
    u16* wt_q = ws;                    // 4 x 512*512 bf16
    u16* wt_k = wt_q + 262144;
    u16* wt_v = wt_k + 262144;
    u16* wt_o = wt_v + 262144;
    u16* Aq = wt_o + 262144;           // converted activations, each 2*2048*512 bf16
    u16* Ak = Aq + 2097152;
    u16* Av = Ak + 2097152;
    u16* Qb = Av + 2097152;            // projected Q/K/V bf16 (Q pre-scaled by 1/8)
    u16* Kb = Qb + 2097152;
    u16* Vb = Kb + 2097152;
    u16* Vt = Vb + 2097152;            // V transposed (B,H,DH,S)
    u16* Ab = Vt + 2097152;            // attention output (merged heads) bf16
    // aliases over the Aq/Ak/Av region (dead after qkv_gemm):
    u16* Opart = Aq;                                          // 2*16*2048*64 bf16 = 8.4 MB
    float* ML = (float*)(Aq + KSPLIT * 16 * S_LEN * DHEAD);   // 0.5 MB, ends at Aq+4.46M u16
    int* mflags = (int*)(Aq + 5500000);                       // 2048 ints, inside dead Av region

    dim3 tb(32, 32);
    cvt_qkv_kernel<<<dim3(1024, 1, 3), 256, 0, stream>>>(q_in, k_in, v_in, Aq);
    transpose_w_kernel<<<dim3(16, 16, 4), tb, 0, stream>>>(wq, wk, wv, wo, wt_q);
    qkv_gemm_kernel<<<dim3(4, 32, 3), 256, 0, stream>>>(Aq, Ak, Av, wt_q, wt_k, wt_v,
                                                        bq, bk, bv, Qb, Kb, Vb);
    mask_flags_kernel<<<2048, 256, 0, stream>>>(mask, mflags);  // after qkv (aliases Av)
    transpose_v_kernel<<<dim3(2, 64, 16), tb, 0, stream>>>(Vb, Vt);
    attn_kernel<<<dim3(32, 16, KSPLIT), 256, 0, stream>>>(Qb, Kb, Vt, mask, mflags, Opart, ML);
    attn_combine_kernel<<<8192, 256, 0, stream>>>(Opart, ML, Ab);
    out_gemm_kernel<<<dim3(4, 32), 256, 0, stream>>>(Ab, wt_o, bo, (float*)d_out);
}